// Round 1
// baseline (391.093 us; speedup 1.0000x reference)
//
#include <hip/hip_runtime.h>
#include <hip/hip_bf16.h>

// Problem constants (B,T,H fixed by setup_inputs)
#define B_ 16
#define T_ 8192
#define H_ 256
#define M_ (B_ * T_)   // 131072 rows
#define STRIDE_ 8      // window over [max(0,t-8), t], count = min(t+1, 9)

typedef __bf16 bf16x8 __attribute__((ext_vector_type(8)));
typedef float f32x4 __attribute__((ext_vector_type(4)));

// round-to-nearest-even fp32 -> bf16 bits
__device__ __forceinline__ unsigned short f2bf(float f) {
  unsigned u = __builtin_bit_cast(unsigned, f);
  u += 0x7fffu + ((u >> 16) & 1u);
  return (unsigned short)(u >> 16);
}

// async global -> LDS, 16 bytes per lane (global_load_lds_dwordx4)
__device__ __forceinline__ void load_lds16(const void* g, void* l) {
  __builtin_amdgcn_global_load_lds(
      (const __attribute__((address_space(1))) void*)g,
      (__attribute__((address_space(3))) void*)l, 16, 0, 0);
}

// ---------------------------------------------------------------------------
// Kernel 1: build Wpk = 8 per-iteration swizzled LDS images of B^T, bf16.
// (unchanged from previous version)
// ---------------------------------------------------------------------------
__global__ __launch_bounds__(256) void wcat_kernel(
    const float* __restrict__ Wl, const float* __restrict__ bl,
    const float* __restrict__ Wm, const float* __restrict__ bm,
    unsigned short* __restrict__ Wpk, float* __restrict__ bias) {
  const int e = blockIdx.x * 256 + threadIdx.x;
  const int it = e >> 14;
  const int r = (e >> 6) & 255;
  const int col = e & 63;
  const int cp = col >> 3;
  const int ei = col & 7;
  const int c = cp ^ (r & 7);
  const int k = it * 32 + (c & 3) * 8 + ei + ((c < 4) ? 0 : 256);
  const float w = (k < 256) ? Wl[r * 256 + k] : Wm[r * 256 + (k - 256)];
  Wpk[e] = f2bf(w);
  if (e < 256) bias[e] = bl[e] + bm[e];
}

// ---------------------------------------------------------------------------
// Kernel 2 (fused): out[M,256] = [x | winmean(x)] @ Wcat^T + bias
// Change vs previous version: cross-iteration REGISTER PREFETCH of the x
// window (T14). x-loads for iter it+1 are issued after the pre-MFMA barrier
// of iter it, so their ~900-cycle HBM latency hides under the MFMA phase +
// loop-top barrier instead of stalling the means-compute at point of use.
// Both barriers remain __syncthreads() (no counted-vmcnt race surface).
// it-loop fully unrolled so v[it&1] is compile-time indexed (no scratch).
// grid: 2048 x 256
// ---------------------------------------------------------------------------
__global__ __launch_bounds__(256, 3) void fused_kernel(
    const float* __restrict__ x,            // [M, 256] fp32
    const unsigned short* __restrict__ Wpk, // 8 x [256][64] swizzled bf16
    const float* __restrict__ bias,         // [256]
    float* __restrict__ out) {              // [M, 256] fp32
  __shared__ __align__(16) unsigned short As[64 * 64];   //  8 KB swizzled
  __shared__ __align__(16) unsigned short Bs[256 * 64];  // 32 KB swizzled
  const int tid = threadIdx.x;
  const int m0 = blockIdx.x << 6;
  const int tb0 = m0 & (T_ - 1);   // token of tile row 0 within its batch
  const int w = tid >> 6;
  const int l = tid & 63;
  const int wc = w << 6;           // wave N offset (all waves share rows)
  const int lm = l & 15;
  const int kqc = l >> 4;          // k-chunk index within 32 (0..3)

  // A staging: col-pair p (16 pairs of 32-col chunk), row-group g (16 x 4 rows)
  const int p = tid & 15, g = tid >> 4;
  const float2* __restrict__ x2 = (const float2*)x;
  unsigned* __restrict__ As32 = (unsigned*)As;

  f32x4 acc[4][4];
#pragma unroll
  for (int i = 0; i < 4; ++i)
#pragma unroll
    for (int j = 0; j < 4; ++j) acc[i][j] = (f32x4){0.f, 0.f, 0.f, 0.f};

  // x-row register double buffer: 12 rows (8-row halo + 4 own) x float2
  float2 v[2][12];
  // prologue: issue it=0 window loads
#pragma unroll
  for (int i = 0; i < 12; ++i) {
    const int rl = (g << 2) - 8 + i;
    float2 val = {0.f, 0.f};
    if (tb0 + rl >= 0)                      // zero before batch start
      val = x2[(size_t)(m0 + rl) * 128 + p];
    v[0][i] = val;
  }

#pragma unroll
  for (int it = 0; it < 8; ++it) {
    __syncthreads();  // prev iter's ds_reads done; drains prefetch residual

    // --- B: copy 32 KB pre-swizzled image (lane-linear, async) ---
    const unsigned short* bsrc = Wpk + (it << 14);
#pragma unroll
    for (int rnd = 0; rnd < 8; ++rnd) {
      const int f = tid + (rnd << 8);
      load_lds16(bsrc + f * 8, &Bs[f * 8]);
    }

    // --- A: means from already-resident registers, emit x-pairs + mean-pairs
    float sx = 0.f, sy = 0.f;
#pragma unroll
    for (int i = 0; i < 8; ++i) {
      sx += v[it & 1][i].x;
      sy += v[it & 1][i].y;
    }
#pragma unroll
    for (int rr = 0; rr < 4; ++rr) {
      sx += v[it & 1][rr + 8].x;
      sy += v[it & 1][rr + 8].y;
      const int r = (g << 2) + rr;
      const int t = tb0 + r;
      const float inv =
          (t >= STRIDE_) ? (1.f / 9.f) : __builtin_amdgcn_rcpf((float)(t + 1));
      const unsigned xp = (unsigned)f2bf(v[it & 1][rr + 8].x) |
                          ((unsigned)f2bf(v[it & 1][rr + 8].y) << 16);
      const unsigned mp =
          (unsigned)f2bf(sx * inv) | ((unsigned)f2bf(sy * inv) << 16);
      const int sw = r & 7;
      As32[r * 32 + (((p >> 2) ^ sw) << 2) + (p & 3)] = xp;        // chunks 0-3
      As32[r * 32 + (((4 + (p >> 2)) ^ sw) << 2) + (p & 3)] = mp;  // chunks 4-7
      sx -= v[it & 1][rr].x;
      sy -= v[it & 1][rr].y;
    }
    __syncthreads();  // ds_writes visible + global_load_lds drained

    // --- X prefetch for it+1: issue now, lands during MFMA + next barrier ---
    if (it < 7) {
#pragma unroll
      for (int i = 0; i < 12; ++i) {
        const int rl = (g << 2) - 8 + i;
        float2 val = {0.f, 0.f};
        if (tb0 + rl >= 0)
          val = x2[(size_t)(m0 + rl) * 128 + ((it + 1) << 4) + p];
        v[(it + 1) & 1][i] = val;
      }
      // pin: prefetch must issue before the MFMA region, not sink below it
      __builtin_amdgcn_sched_barrier(0);
    }

    // --- MFMA: K=64 in two k-steps of 32 ---
#pragma unroll
    for (int kk = 0; kk < 2; ++kk) {
      const int cc = (kk << 2) + kqc;
      bf16x8 a[4], bb[4];
#pragma unroll
      for (int i = 0; i < 4; ++i) {
        const int R = (i << 4) + lm;
        a[i] = *(const bf16x8*)&As[R * 64 + ((cc ^ (R & 7)) << 3)];
      }
#pragma unroll
      for (int j = 0; j < 4; ++j) {
        const int R = wc + (j << 4) + lm;
        bb[j] = *(const bf16x8*)&Bs[R * 64 + ((cc ^ (R & 7)) << 3)];
      }
#pragma unroll
      for (int i = 0; i < 4; ++i)
#pragma unroll
        for (int j = 0; j < 4; ++j)
          acc[i][j] = __builtin_amdgcn_mfma_f32_16x16x32_bf16(a[i], bb[j],
                                                              acc[i][j], 0, 0, 0);
    }
  }

  // epilogue: C/D layout col = l&15, row = (l>>4)*4 + reg
  const int r0 = (l >> 4) << 2;
#pragma unroll
  for (int j = 0; j < 4; ++j) {
    const int o = wc + (j << 4) + lm;
    const float bs = bias[o];
#pragma unroll
    for (int i = 0; i < 4; ++i) {
      const size_t mr = (size_t)(m0 + (i << 4) + r0);
#pragma unroll
      for (int r = 0; r < 4; ++r) out[(mr + r) * 256 + o] = acc[i][j][r] + bs;
    }
  }
}

// ---------------------------------------------------------------------------
extern "C" void kernel_launch(void* const* d_in, const int* in_sizes, int n_in,
                              void* d_out, int out_size, void* d_ws, size_t ws_size,
                              hipStream_t stream) {
  const float* x  = (const float*)d_in[0];
  const float* Wl = (const float*)d_in[1];
  const float* bl = (const float*)d_in[2];
  const float* Wm = (const float*)d_in[3];
  const float* bm = (const float*)d_in[4];
  float* out = (float*)d_out;

  // workspace: Wpk 8x256x64 bf16 (256 KiB) + bias 256 f32 (1 KiB)
  char* ws = (char*)d_ws;
  unsigned short* Wpk = (unsigned short*)ws;
  float* bias = (float*)(ws + (size_t)8 * 256 * 64 * 2);

  wcat_kernel<<<512, 256, 0, stream>>>(Wl, bl, Wm, bm, Wpk, bias);
  fused_kernel<<<2048, 256, 0, stream>>>(x, Wpk, bias, out);
}